// Round 3
// baseline (540.264 us; speedup 1.0000x reference)
//
#include <hip/hip_runtime.h>

#define NPART 32
#define DIM   256
#define BATCH 8192

// ---- workspace offsets (float units) ----
#define OFF_S     0u          // [8192] s[b]
#define OFF_DWP   8192u       // [256][32][256] dW partials (8MB)
#define OFF_WG    2105344u    // [32][256] W_grads
#define OFF_COVP  2113536u    // [16][256][256] cov partials (4MB, full tiles via mirror)
#define OFF_H     3162112u    // [256][256]
#define OFF_EA    3227648u    // NS E ping
#define OFF_EB    3293184u    // NS E pong
#define OFF_XA    3358720u    // NS X ping
#define OFF_XB    3424256u    // NS X pong
#define OFF_SVGD  3489792u    // [32][256]
#define OFF_LLP   3497984u    // 256 doubles (512 floats)
#define OFF_ACCP  3498496u    // 256 floats
#define OFF_TAU   3498752u    // 1 uint
#define OFF_BAR   3498756u    // 2 uints: barrier cnt, gen
// total ~14 MB of d_ws

#define NBLK 256u

__constant__ int c_pi[10] = {0,0,0,0,1,1,1,2,2,3};
__constant__ int c_pj[10] = {0,1,2,3,1,2,3,2,3,3};

__device__ __forceinline__ float dot4(float4 a, float4 b) {
  return a.x*b.x + a.y*b.y + a.z*b.z + a.w*b.w;
}

// ---------------------------------------------------------------------------
// software grid barrier: snapshot gen -> release fence -> arrive -> last
// resets cnt and release-bumps gen; waiters acquire-spin on gen. All blocks
// co-resident (grid 256 = 1 block/CU, launch_bounds(256,1)).
// ---------------------------------------------------------------------------
__device__ __forceinline__ void gridbar(unsigned* cnt, unsigned* gen) {
  __syncthreads();
  if (threadIdx.x == 0) {
    unsigned g = __hip_atomic_load(gen, __ATOMIC_RELAXED, __HIP_MEMORY_SCOPE_AGENT);
    __threadfence();   // release: writeback this XCD's L2 (covers whole block's stores)
    unsigned a = __hip_atomic_fetch_add(cnt, 1u, __ATOMIC_ACQ_REL, __HIP_MEMORY_SCOPE_AGENT);
    if (a == NBLK - 1u) {
      __hip_atomic_store(cnt, 0u, __ATOMIC_RELAXED, __HIP_MEMORY_SCOPE_AGENT);
      __hip_atomic_fetch_add(gen, 1u, __ATOMIC_RELEASE, __HIP_MEMORY_SCOPE_AGENT);
    } else {
      while (__hip_atomic_load(gen, __ATOMIC_ACQUIRE, __HIP_MEMORY_SCOPE_AGENT) == g)
        __builtin_amdgcn_s_sleep(2);
    }
    __threadfence();   // acquire: invalidate L1 before post-barrier reads
  }
  __syncthreads();
}

// ---------------------------------------------------------------------------
// K1 fused: z = W@X^T -> p -> dzdy -> {s[b], ll/acc partials, dW partials}
// grid 256 x 256; also zero-inits barrier counters + tau for k_master
// ---------------------------------------------------------------------------
__global__ __launch_bounds__(256) void k_fused1(
    const float4* __restrict__ X4, const float* __restrict__ y,
    const float4* __restrict__ W4,
    float* __restrict__ s_ws, float4* __restrict__ dWp4,
    double* __restrict__ llpart, float* __restrict__ accpart,
    unsigned int* __restrict__ tau_bits, unsigned int* __restrict__ bar)
{
  __shared__ float4 Wl[32][65];
  __shared__ float4 Xl[32][65];
  __shared__ float  dzl[32][36];
  __shared__ double llred[16];
  __shared__ float  accred[16];
  const int t = threadIdx.x, blk = blockIdx.x;
  const int base = blk*32;

  if (blk == 0 && t == 0) { bar[0] = 0u; bar[1] = 0u; *tau_bits = 0u; }

  #pragma unroll
  for (int i = 0; i < 8; ++i) { int idx = t + i*256; Wl[idx>>6][idx&63] = W4[idx]; }
  #pragma unroll
  for (int i = 0; i < 8; ++i) {
    int idx = t + i*256;
    Xl[idx>>6][idx&63] = X4[(base + (idx>>6))*64 + (idx&63)];
  }
  __syncthreads();

  const int nb = t & 15, bs = t >> 4;
  const int n0 = nb, n1 = nb + 16;

  float z00=0.f, z01=0.f, z10=0.f, z11=0.f;
  #pragma unroll 8
  for (int c = 0; c < 64; ++c) {
    float4 wa = Wl[n0][c], wb = Wl[n1][c];
    float4 xa = Xl[bs][c], xb = Xl[bs+16][c];
    z00 += dot4(wa, xa); z01 += dot4(wa, xb);
    z10 += dot4(wb, xa); z11 += dot4(wb, xb);
  }
  const int b0 = base + bs, b1 = base + bs + 16;
  const float y0 = y[b0], y1 = y[b1];

  float p00 = 1.f/(1.f+expf(-z00)), p01 = 1.f/(1.f+expf(-z01));
  float p10 = 1.f/(1.f+expf(-z10)), p11 = 1.f/(1.f+expf(-z11));

  auto dzf = [](float p, float yv) {
    float pq = p - p*p;
    return pq*(yv - p)/(pq + 1e-8f);
  };
  float dz00 = dzf(p00, y0), dz01 = dzf(p01, y1);
  float dz10 = dzf(p10, y0), dz11 = dzf(p11, y1);

  float sp0 = p00 + p10, sp1 = p01 + p11;
  float sd0 = dz00 + dz10, sd1 = dz01 + dz11;
  #pragma unroll
  for (int m = 8; m >= 1; m >>= 1) {
    sp0 += __shfl_xor(sp0, m); sp1 += __shfl_xor(sp1, m);
    sd0 += __shfl_xor(sd0, m); sd1 += __shfl_xor(sd1, m);
  }
  const float m0 = sd0*(1.f/32.f), m1 = sd1*(1.f/32.f);
  float q0 = (dz00-m0)*(dz00-m0) + (dz10-m0)*(dz10-m0);
  float q1 = (dz01-m1)*(dz01-m1) + (dz11-m1)*(dz11-m1);
  #pragma unroll
  for (int m = 8; m >= 1; m >>= 1) {
    q0 += __shfl_xor(q0, m); q1 += __shfl_xor(q1, m);
  }

  dzl[bs][n0]    = dz00; dzl[bs][n1]    = dz10;
  dzl[bs+16][n0] = dz01; dzl[bs+16][n1] = dz11;

  if (nb == 0) {
    s_ws[b0] = q0; s_ws[b1] = q1;
    float yp0 = sp0*(1.f/32.f), yp1 = sp1*(1.f/32.f);
    double ll = (double)(y0*logf(yp0+1e-3f) + (1.f-y0)*logf(1.f-yp0+1e-3f))
              + (double)(y1*logf(yp1+1e-3f) + (1.f-y1)*logf(1.f-yp1+1e-3f));
    float ac = (((y0 > 0.5f) == (yp0 > 0.5f)) ? 1.f : 0.f)
             + (((y1 > 0.5f) == (yp1 > 0.5f)) ? 1.f : 0.f);
    llred[bs] = ll; accred[bs] = ac;
  }
  __syncthreads();

  // dW partials: dWp[blk][n][d] = sum_b dzl[b][n] * Xl[b][d]
  const int n = t >> 3, c = t & 7;
  float4 acc[8];
  #pragma unroll
  for (int m = 0; m < 8; ++m) acc[m] = make_float4(0.f,0.f,0.f,0.f);
  #pragma unroll 4
  for (int b = 0; b < 32; ++b) {
    float dzv = dzl[b][n];
    #pragma unroll
    for (int m = 0; m < 8; ++m) {
      float4 xv = Xl[b][c + 8*m];
      acc[m].x += dzv*xv.x; acc[m].y += dzv*xv.y;
      acc[m].z += dzv*xv.z; acc[m].w += dzv*xv.w;
    }
  }
  #pragma unroll
  for (int m = 0; m < 8; ++m)
    dWp4[blk*2048 + n*64 + c + 8*m] = acc[m];

  if (t == 0) {
    double L = 0.0;
    for (int i = 0; i < 16; ++i) L += llred[i];
    llpart[blk] = L;
  } else if (t == 1) {
    float A = 0.f;
    for (int i = 0; i < 16; ++i) A += accred[i];
    accpart[blk] = A;
  }
}

// ---------------------------------------------------------------------------
// NS GEMM tile helper: 32x32 tile of Cout = (Cadd? Cadd + A@B : A@B), 256x256
// ---------------------------------------------------------------------------
__device__ __forceinline__ void ns_gemm(
    float* smemf, const float* __restrict__ A, const float* __restrict__ B,
    const float* __restrict__ Cadd, float* __restrict__ Cout,
    int tileid, int t)
{
  float* At = smemf;          // [32][34] transposed A tile
  float* Bs = smemf + 1088;   // [32][34]
  const int i0 = (tileid >> 3)*32, j0 = (tileid & 7)*32;
  const int ti = t & 15, tj = t >> 4;
  const int srow = t >> 3, sc4 = t & 7;
  const float4* A4 = (const float4*)A;
  const float4* B4 = (const float4*)B;
  float acc00=0.f, acc01=0.f, acc10=0.f, acc11=0.f;

  for (int k0 = 0; k0 < 8; ++k0) {
    __syncthreads();
    float4 av = A4[(i0+srow)*64 + k0*8 + sc4];
    float4 bv = B4[(k0*32+srow)*64 + (j0>>2) + sc4];
    At[(sc4*4+0)*34+srow]=av.x; At[(sc4*4+1)*34+srow]=av.y;
    At[(sc4*4+2)*34+srow]=av.z; At[(sc4*4+3)*34+srow]=av.w;
    Bs[srow*34+sc4*4+0]=bv.x; Bs[srow*34+sc4*4+1]=bv.y;
    Bs[srow*34+sc4*4+2]=bv.z; Bs[srow*34+sc4*4+3]=bv.w;
    __syncthreads();
    #pragma unroll
    for (int kk = 0; kk < 32; ++kk) {
      float2 a = *(const float2*)&At[kk*34+2*ti];
      float2 b = *(const float2*)&Bs[kk*34+2*tj];
      acc00 += a.x*b.x; acc01 += a.x*b.y;
      acc10 += a.y*b.x; acc11 += a.y*b.y;
    }
  }
  const int gi = i0 + 2*ti, gj = j0 + 2*tj;
  if (Cadd) {
    Cout[gi*256+gj]       = Cadd[gi*256+gj]       + acc00;
    Cout[gi*256+gj+1]     = Cadd[gi*256+gj+1]     + acc01;
    Cout[(gi+1)*256+gj]   = Cadd[(gi+1)*256+gj]   + acc10;
    Cout[(gi+1)*256+gj+1] = Cadd[(gi+1)*256+gj+1] + acc11;
  } else {
    Cout[gi*256+gj]       = acc00; Cout[gi*256+gj+1]     = acc01;
    Cout[(gi+1)*256+gj]   = acc10; Cout[(gi+1)*256+gj+1] = acc11;
  }
}

// ---------------------------------------------------------------------------
// K2 persistent master: finalize+cov+rbf -> H+svgd -> nsinit -> NS -> kfac
// grid 256 x 256, 1 block/CU guaranteed co-resident.
// ---------------------------------------------------------------------------
__global__ __launch_bounds__(256, 1) void k_master(
    const float4* __restrict__ X4, const float* __restrict__ W,
    float* __restrict__ out, float* __restrict__ ws)
{
  float* s_ws = ws + OFF_S;
  float* dWp  = ws + OFF_DWP;
  float* Wg   = ws + OFF_WG;
  float* covp = ws + OFF_COVP;
  float* H    = ws + OFF_H;
  float* Ebuf[2] = { ws + OFF_EA, ws + OFF_EB };
  float* Xbuf[2] = { ws + OFF_XA, ws + OFF_XB };
  float* svgd = ws + OFF_SVGD;
  double* llp = (double*)(ws + OFF_LLP);
  float* accp = ws + OFF_ACCP;
  unsigned* taup = (unsigned*)(ws + OFF_TAU);
  unsigned* bar  = (unsigned*)(ws + OFF_BAR);

  __shared__ __align__(16) float smemf[10432];   // ~41.7 KB, role-overlaid
  const int t = threadIdx.x, blk = blockIdx.x;

  // ======================= P0 =======================
  if (blk < 32) {
    // finalize W_grads row blk (N_TRAIN/BATCH == 1 exactly)
    float sum = 0.f;
    #pragma unroll 8
    for (int k = 0; k < 256; ++k) sum += dWp[k*8192 + blk*256 + t];
    Wg[blk*256 + t] = sum - W[blk*256 + t];
  } else if (blk == 32) {
    if (t == 0) {
      double L = 0.0;
      for (int k = 0; k < 256; ++k) L += llp[k];
      out[0] = (float)(L / 8192.0);
    } else if (t == 1) {
      float A = 0.f;
      for (int k = 0; k < 256; ++k) A += accp[k];
      out[1] = A / 8192.f;
    }
  } else if (blk >= 64 && blk < 224) {
    // weighted SYRK cov partials; 10 upper tile-pairs x 16 K-chunks of 512
    float4* Ad = (float4*)&smemf[0];      // [32][17]
    float4* Ae = (float4*)&smemf[2176];   // [32][17]
    const int p = (blk - 64) >> 4, z = (blk - 64) & 15;
    const int dt = c_pi[p]*16, et = c_pj[p]*16;   // float4 units
    const int tx = t & 15, ty = t >> 4;
    float acc[4][4];
    #pragma unroll
    for (int i = 0; i < 4; ++i)
      #pragma unroll
      for (int j = 0; j < 4; ++j) acc[i][j] = 0.f;

    for (int sub = 0; sub < 16; ++sub) {
      const int b0 = z*512 + sub*32;
      __syncthreads();
      #pragma unroll
      for (int i = 0; i < 2; ++i) {
        int idx = t + i*256; int row = idx>>4, c4 = idx&15;
        float sv = s_ws[b0+row];
        float4 xv = X4[(b0+row)*64 + dt + c4];
        Ad[row*17+c4] = make_float4(xv.x*sv, xv.y*sv, xv.z*sv, xv.w*sv);
        Ae[row*17+c4] = X4[(b0+row)*64 + et + c4];
      }
      __syncthreads();
      #pragma unroll 4
      for (int b = 0; b < 32; ++b) {
        float4 a = Ad[b*17+tx], e = Ae[b*17+ty];
        acc[0][0]+=a.x*e.x; acc[0][1]+=a.x*e.y; acc[0][2]+=a.x*e.z; acc[0][3]+=a.x*e.w;
        acc[1][0]+=a.y*e.x; acc[1][1]+=a.y*e.y; acc[1][2]+=a.y*e.z; acc[1][3]+=a.y*e.w;
        acc[2][0]+=a.z*e.x; acc[2][1]+=a.z*e.y; acc[2][2]+=a.z*e.z; acc[2][3]+=a.z*e.w;
        acc[3][0]+=a.w*e.x; acc[3][1]+=a.w*e.y; acc[3][2]+=a.w*e.z; acc[3][3]+=a.w*e.w;
      }
    }
    float* cz = covp + (unsigned)z*65536u;
    float4* cz4 = (float4*)cz;
    #pragma unroll
    for (int i = 0; i < 4; ++i) {
      int gd = dt*4 + tx*4 + i;
      cz4[gd*64 + et + ty] = make_float4(acc[i][0], acc[i][1], acc[i][2], acc[i][3]);
    }
    if (dt != et) {  // mirror write so H-phase reads are always coalesced
      #pragma unroll
      for (int i = 0; i < 4; ++i) {
        int gd = dt*4 + tx*4 + i;
        #pragma unroll
        for (int j = 0; j < 4; ++j)
          cz[((et+ty)*4 + j)*256 + gd] = acc[i][j];
      }
    }
  } else if (blk == 255) {
    // rbf part 1: pd, exact median (256-thread bitonic), kxy, sumk
    float* Wf   = &smemf[0];      // [32][260]
    float* pd   = &smemf[8320];   // 1024
    float* sb   = &smemf[9344];   // 1024 (sort buf; becomes kx after median)
    float* sumk = &smemf[10368];  // 32
    float* hshp = &smemf[10400];
    for (int i = t; i < 8192; i += 256)
      Wf[(i>>8)*260 + (i&255)] = W[i];
    __syncthreads();
    for (int pp = t; pp < 1024; pp += 256) {
      int i = pp >> 5, j = pp & 31;
      const float4* wa = (const float4*)&Wf[i*260];
      const float4* wb = (const float4*)&Wf[j*260];
      float d2 = 0.f;
      #pragma unroll 8
      for (int c = 0; c < 64; ++c) {
        float4 a = wa[c], b = wb[c];
        float dx=a.x-b.x, dy=a.y-b.y, dz=a.z-b.z, dw=a.w-b.w;
        d2 += dx*dx + dy*dy + dz*dz + dw*dw;
      }
      pd[pp] = d2; sb[pp] = d2;
    }
    __syncthreads();
    for (int k = 2; k <= 1024; k <<= 1) {
      for (int j = k >> 1; j > 0; j >>= 1) {
        #pragma unroll 1
        for (int m = t; m < 1024; m += 256) {
          int ixj = m ^ j;
          if (ixj > m) {
            float a = sb[m], b = sb[ixj];
            bool up = ((m & k) == 0);
            if ((a > b) == up) { sb[m] = b; sb[ixj] = a; }
          }
        }
        __syncthreads();
      }
    }
    if (t == 0) hshp[0] = 0.5f*(sb[511] + sb[512]) / logf(33.0f);
    __syncthreads();
    const float h = hshp[0];
    for (int pp = t; pp < 1024; pp += 256)
      sb[pp] = expf(-pd[pp]/h);     // sb now holds kxy
    __syncthreads();
    if (t < 32) {
      float s = 0.f;
      #pragma unroll
      for (int j = 0; j < 32; ++j) s += sb[t*32 + j];
      sumk[t] = s;
    }
  }
  gridbar(bar, bar+1);

  // ======================= P1 =======================
  if (blk < 128) {
    // H rows 2blk, 2blk+1: sum 16 slabs, scale, ridge; row |.| sum -> tau
    for (int rr = 0; rr < 2; ++rr) {
      const int d = blk*2 + rr;
      float sum = 0.f;
      #pragma unroll
      for (int z = 0; z < 16; ++z) sum += covp[(unsigned)z*65536u + d*256 + t];
      float h = sum * (1.f/262144.f) + ((d == t) ? 0.01f : 0.f);
      H[d*256 + t] = h;
      float a = fabsf(h);
      #pragma unroll
      for (int m = 32; m >= 1; m >>= 1) a += __shfl_xor(a, m);
      if ((t & 63) == 0) smemf[rr*4 + (t >> 6)] = a;
    }
    __syncthreads();
    if (t < 2) {
      float r = smemf[t*4] + smemf[t*4+1] + smemf[t*4+2] + smemf[t*4+3];
      atomicMax(taup, __float_as_uint(r));
    }
  } else if (blk == 255) {
    // rbf part 2: svgd = (kxy@(Wg - c2*W) + c2*sumk.*W) / 32
    float* Wf   = &smemf[0];
    float* sb   = &smemf[9344];   // kxy
    float* sumk = &smemf[10368];
    const float h = smemf[10400];
    const float c2 = 2.f/h;
    for (int i = t; i < 8192; i += 256) {
      int n = i>>8, d = i&255;
      Wf[n*260 + d] = Wg[i] - c2*Wf[n*260 + d];    // G = Wg - c2*W (in place)
    }
    __syncthreads();
    for (int o = t; o < 8192; o += 256) {
      int oi = o>>8, oc = o&255;
      float acc = 0.f;
      #pragma unroll 8
      for (int jj = 0; jj < 32; ++jj)
        acc += sb[oi*32 + jj] * Wf[jj*260 + oc];
      float r = (acc + c2*sumk[oi]*W[o]) * (1.f/32.f);
      svgd[o] = r;
      out[2 + o] = r;     // d_out+2 only 8B aligned -> scalar stores
    }
  }
  gridbar(bar, bar+1);

  // ======================= P2: NS init =======================
  {
    const float tau = __uint_as_float(
        __hip_atomic_load(taup, __ATOMIC_RELAXED, __HIP_MEMORY_SCOPE_AGENT));
    const float alpha = 2.f/(tau + 0.01f);
    const float h = H[blk*256 + t];
    Ebuf[0][blk*256 + t] = ((blk == t) ? 1.f : 0.f) - alpha*h;
    Xbuf[0][blk*256 + t] = (blk == t) ? alpha : 0.f;
  }
  gridbar(bar, bar+1);

  // ======================= P3..P8: 6 dual NS squarings =======================
  int cur = 0;
  for (int it = 0; it < 6; ++it) {
    if (blk < 128) {
      if (blk < 64) ns_gemm(smemf, Ebuf[cur], Ebuf[cur], nullptr, Ebuf[cur^1], blk, t);
      else          ns_gemm(smemf, Xbuf[cur], Ebuf[cur], Xbuf[cur], Xbuf[cur^1], blk-64, t);
    }
    gridbar(bar, bar+1);
    cur ^= 1;
  }
  // ======================= P9: final X-only step (residual E^128) ===========
  if (blk < 64)
    ns_gemm(smemf, Xbuf[cur], Ebuf[cur], Xbuf[cur], Xbuf[cur^1], blk, t);
  gridbar(bar, bar+1);
  float* Xf = Xbuf[cur^1];

  // ======================= P10: kfac = svgd @ Hinv =======================
  if (blk < 32) {
    float* sv = &smemf[0];
    sv[t] = svgd[blk*256 + t];
    __syncthreads();
    float acc = 0.f;
    #pragma unroll 8
    for (int k = 0; k < 256; ++k) acc += sv[k] * Xf[k*256 + t];
    out[2 + 8192 + blk*256 + t] = acc;
  }
}

// ---------------------------------------------------------------------------
extern "C" void kernel_launch(void* const* d_in, const int* in_sizes, int n_in,
                              void* d_out, int out_size, void* d_ws, size_t ws_size,
                              hipStream_t stream) {
  (void)in_sizes; (void)n_in; (void)out_size; (void)ws_size;
  const float* X = (const float*)d_in[0];
  const float* y = (const float*)d_in[1];
  const float* W = (const float*)d_in[2];
  float* out = (float*)d_out;
  float* ws  = (float*)d_ws;

  k_fused1<<<256, 256, 0, stream>>>(
      (const float4*)X, y, (const float4*)W,
      ws + OFF_S, (float4*)(ws + OFF_DWP),
      (double*)(ws + OFF_LLP), ws + OFF_ACCP,
      (unsigned int*)(ws + OFF_TAU), (unsigned int*)(ws + OFF_BAR));

  k_master<<<256, 256, 0, stream>>>((const float4*)X, W, out, ws);
}

// Round 5
// 423.589 us; speedup vs baseline: 1.2754x; 1.2754x over previous
//
#include <hip/hip_runtime.h>
#include <hip/hip_cooperative_groups.h>

namespace cg = cooperative_groups;

#define NPART 32
#define DIM   256
#define BATCH 8192

// ---- workspace offsets (float units) ----
#define OFF_S     0u          // [8192] s[b]
#define OFF_DWP   8192u       // [256][32][256] dW partials (8MB)
#define OFF_WG    2105344u    // [32][256] W_grads
#define OFF_COVP  2113536u    // [16][256][256] cov partials (4MB, full via mirror)
#define OFF_H     3162112u    // [256][256]
#define OFF_EA    3227648u    // NS E ping
#define OFF_EB    3293184u    // NS E pong
#define OFF_XA    3358720u    // NS X ping
#define OFF_XB    3424256u    // NS X pong
#define OFF_SVGD  3489792u    // [32][256]
#define OFF_LLP   3497984u    // 256 doubles (512 floats)
#define OFF_ACCP  3498496u    // 256 floats
#define OFF_TAU   3498752u    // 1 uint
// total ~14 MB of d_ws

#define NBLK 256u

__constant__ int c_pi[10] = {0,0,0,0,1,1,1,2,2,3};
__constant__ int c_pj[10] = {0,1,2,3,1,2,3,2,3,3};

__device__ __forceinline__ float dot4(float4 a, float4 b) {
  return a.x*b.x + a.y*b.y + a.z*b.z + a.w*b.w;
}

// ---------------------------------------------------------------------------
// NS GEMM tile helper: 32x32 tile of Cout = (Cadd? Cadd + A@B : A@B), 256x256
// ---------------------------------------------------------------------------
__device__ __forceinline__ void ns_gemm(
    float* smemf, const float* __restrict__ A, const float* __restrict__ B,
    const float* __restrict__ Cadd, float* __restrict__ Cout,
    int tileid, int t)
{
  float* At = smemf;          // [32][34] transposed A tile
  float* Bs = smemf + 1088;   // [32][34]
  const int i0 = (tileid >> 3)*32, j0 = (tileid & 7)*32;
  const int ti = t & 15, tj = t >> 4;
  const int srow = t >> 3, sc4 = t & 7;
  const float4* A4 = (const float4*)A;
  const float4* B4 = (const float4*)B;
  float acc00=0.f, acc01=0.f, acc10=0.f, acc11=0.f;

  for (int k0 = 0; k0 < 8; ++k0) {
    __syncthreads();
    float4 av = A4[(i0+srow)*64 + k0*8 + sc4];
    float4 bv = B4[(k0*32+srow)*64 + (j0>>2) + sc4];
    At[(sc4*4+0)*34+srow]=av.x; At[(sc4*4+1)*34+srow]=av.y;
    At[(sc4*4+2)*34+srow]=av.z; At[(sc4*4+3)*34+srow]=av.w;
    Bs[srow*34+sc4*4+0]=bv.x; Bs[srow*34+sc4*4+1]=bv.y;
    Bs[srow*34+sc4*4+2]=bv.z; Bs[srow*34+sc4*4+3]=bv.w;
    __syncthreads();
    #pragma unroll
    for (int kk = 0; kk < 32; ++kk) {
      float2 a = *(const float2*)&At[kk*34+2*ti];
      float2 b = *(const float2*)&Bs[kk*34+2*tj];
      acc00 += a.x*b.x; acc01 += a.x*b.y;
      acc10 += a.y*b.x; acc11 += a.y*b.y;
    }
  }
  const int gi = i0 + 2*ti, gj = j0 + 2*tj;
  if (Cadd) {
    Cout[gi*256+gj]       = Cadd[gi*256+gj]       + acc00;
    Cout[gi*256+gj+1]     = Cadd[gi*256+gj+1]     + acc01;
    Cout[(gi+1)*256+gj]   = Cadd[(gi+1)*256+gj]   + acc10;
    Cout[(gi+1)*256+gj+1] = Cadd[(gi+1)*256+gj+1] + acc11;
  } else {
    Cout[gi*256+gj]       = acc00; Cout[gi*256+gj+1]     = acc01;
    Cout[(gi+1)*256+gj]   = acc10; Cout[(gi+1)*256+gj+1] = acc11;
  }
}

// ---------------------------------------------------------------------------
// Single persistent cooperative kernel:
// F(z/dzdy/s/dWp) -> fin+cov+rbf1 -> H+rbf2 -> nsinit -> NS x6 -> Xfinal+kfac
// grid 256 x 256, cooperative launch; grid.sync() between phases.
// ---------------------------------------------------------------------------
__global__ __launch_bounds__(256, 1) void k_all(
    const float4* __restrict__ X4, const float* __restrict__ y,
    const float* __restrict__ W, float* __restrict__ out,
    float* __restrict__ ws)
{
  cg::grid_group grid = cg::this_grid();

  float* s_ws = ws + OFF_S;
  float* dWp  = ws + OFF_DWP;
  float* Wg   = ws + OFF_WG;
  float* covp = ws + OFF_COVP;
  float* H    = ws + OFF_H;
  float* Ebuf[2] = { ws + OFF_EA, ws + OFF_EB };
  float* Xbuf[2] = { ws + OFF_XA, ws + OFF_XB };
  float* svgd = ws + OFF_SVGD;
  double* llp = (double*)(ws + OFF_LLP);
  float* accp = ws + OFF_ACCP;
  unsigned* taup = (unsigned*)(ws + OFF_TAU);

  __shared__ __align__(16) float smemf[17856];   // 71.4 KB, role-overlaid
  const int t = threadIdx.x, blk = blockIdx.x;

  // ============ Phase F: z = W@X^T -> dzdy -> s, ll/acc, dW partials ========
  {
    float4* Wl  = (float4*)smemf;            // [32][65]
    float4* Xl  = (float4*)(smemf + 8320);   // [32][65]
    float*  dzl = smemf + 16640;             // [32][36]
    double* llred = (double*)(smemf + 17792);
    float*  accred = smemf + 17824;
    const int base = blk*32;
    const float4* W4 = (const float4*)W;

    if (blk == 0 && t == 0)
      __hip_atomic_store(taup, 0u, __ATOMIC_RELAXED, __HIP_MEMORY_SCOPE_AGENT);

    #pragma unroll
    for (int i = 0; i < 8; ++i) { int idx = t + i*256; Wl[(idx>>6)*65 + (idx&63)] = W4[idx]; }
    #pragma unroll
    for (int i = 0; i < 8; ++i) {
      int idx = t + i*256;
      Xl[(idx>>6)*65 + (idx&63)] = X4[(base + (idx>>6))*64 + (idx&63)];
    }
    __syncthreads();

    const int nb = t & 15, bs = t >> 4;
    const int n0 = nb, n1 = nb + 16;

    float z00=0.f, z01=0.f, z10=0.f, z11=0.f;
    #pragma unroll 8
    for (int c = 0; c < 64; ++c) {
      float4 wa = Wl[n0*65+c], wb = Wl[n1*65+c];
      float4 xa = Xl[bs*65+c], xb = Xl[(bs+16)*65+c];
      z00 += dot4(wa, xa); z01 += dot4(wa, xb);
      z10 += dot4(wb, xa); z11 += dot4(wb, xb);
    }
    const int b0 = base + bs, b1 = base + bs + 16;
    const float y0 = y[b0], y1 = y[b1];

    float p00 = 1.f/(1.f+expf(-z00)), p01 = 1.f/(1.f+expf(-z01));
    float p10 = 1.f/(1.f+expf(-z10)), p11 = 1.f/(1.f+expf(-z11));

    auto dzf = [](float p, float yv) {
      float pq = p - p*p;
      return pq*(yv - p)/(pq + 1e-8f);
    };
    float dz00 = dzf(p00, y0), dz01 = dzf(p01, y1);
    float dz10 = dzf(p10, y0), dz11 = dzf(p11, y1);

    float sp0 = p00 + p10, sp1 = p01 + p11;
    float sd0 = dz00 + dz10, sd1 = dz01 + dz11;
    #pragma unroll
    for (int m = 8; m >= 1; m >>= 1) {
      sp0 += __shfl_xor(sp0, m); sp1 += __shfl_xor(sp1, m);
      sd0 += __shfl_xor(sd0, m); sd1 += __shfl_xor(sd1, m);
    }
    const float m0 = sd0*(1.f/32.f), m1 = sd1*(1.f/32.f);
    float q0 = (dz00-m0)*(dz00-m0) + (dz10-m0)*(dz10-m0);
    float q1 = (dz01-m1)*(dz01-m1) + (dz11-m1)*(dz11-m1);
    #pragma unroll
    for (int m = 8; m >= 1; m >>= 1) {
      q0 += __shfl_xor(q0, m); q1 += __shfl_xor(q1, m);
    }

    dzl[bs*36+n0]      = dz00; dzl[bs*36+n1]      = dz10;
    dzl[(bs+16)*36+n0] = dz01; dzl[(bs+16)*36+n1] = dz11;

    if (nb == 0) {
      s_ws[b0] = q0; s_ws[b1] = q1;
      float yp0 = sp0*(1.f/32.f), yp1 = sp1*(1.f/32.f);
      double ll = (double)(y0*logf(yp0+1e-3f) + (1.f-y0)*logf(1.f-yp0+1e-3f))
                + (double)(y1*logf(yp1+1e-3f) + (1.f-y1)*logf(1.f-yp1+1e-3f));
      float ac = (((y0 > 0.5f) == (yp0 > 0.5f)) ? 1.f : 0.f)
               + (((y1 > 0.5f) == (yp1 > 0.5f)) ? 1.f : 0.f);
      llred[bs] = ll; accred[bs] = ac;
    }
    __syncthreads();

    const int n = t >> 3, c = t & 7;
    float4 acc[8];
    #pragma unroll
    for (int m = 0; m < 8; ++m) acc[m] = make_float4(0.f,0.f,0.f,0.f);
    #pragma unroll 4
    for (int b = 0; b < 32; ++b) {
      float dzv = dzl[b*36+n];
      #pragma unroll
      for (int m = 0; m < 8; ++m) {
        float4 xv = Xl[b*65 + c + 8*m];
        acc[m].x += dzv*xv.x; acc[m].y += dzv*xv.y;
        acc[m].z += dzv*xv.z; acc[m].w += dzv*xv.w;
      }
    }
    float4* dWp4 = (float4*)dWp;
    #pragma unroll
    for (int m = 0; m < 8; ++m)
      dWp4[blk*2048 + n*64 + c + 8*m] = acc[m];

    if (t == 0) {
      double L = 0.0;
      for (int i = 0; i < 16; ++i) L += llred[i];
      llp[blk] = L;
    } else if (t == 1) {
      float A = 0.f;
      for (int i = 0; i < 16; ++i) A += accred[i];
      accp[blk] = A;
    }
  }
  grid.sync();

  // ============ P0: finalize Wg + ll/acc | cov partials | rbf part 1 ========
  if (blk < 32) {
    float sum = 0.f;
    #pragma unroll 8
    for (int k = 0; k < 256; ++k) sum += dWp[k*8192 + blk*256 + t];
    Wg[blk*256 + t] = sum - W[blk*256 + t];
  } else if (blk == 32) {
    if (t == 0) {
      double L = 0.0;
      for (int k = 0; k < 256; ++k) L += llp[k];
      out[0] = (float)(L / 8192.0);
    } else if (t == 1) {
      float A = 0.f;
      for (int k = 0; k < 256; ++k) A += accp[k];
      out[1] = A / 8192.f;
    }
  } else if (blk >= 64 && blk < 224) {
    float4* Ad = (float4*)&smemf[0];      // [32][17]
    float4* Ae = (float4*)&smemf[2176];   // [32][17]
    const int p = (blk - 64) >> 4, z = (blk - 64) & 15;
    const int dt = c_pi[p]*16, et = c_pj[p]*16;
    const int tx = t & 15, ty = t >> 4;
    float acc[4][4];
    #pragma unroll
    for (int i = 0; i < 4; ++i)
      #pragma unroll
      for (int j = 0; j < 4; ++j) acc[i][j] = 0.f;

    for (int sub = 0; sub < 16; ++sub) {
      const int b0 = z*512 + sub*32;
      __syncthreads();
      #pragma unroll
      for (int i = 0; i < 2; ++i) {
        int idx = t + i*256; int row = idx>>4, c4 = idx&15;
        float sv = s_ws[b0+row];
        float4 xv = X4[(b0+row)*64 + dt + c4];
        Ad[row*17+c4] = make_float4(xv.x*sv, xv.y*sv, xv.z*sv, xv.w*sv);
        Ae[row*17+c4] = X4[(b0+row)*64 + et + c4];
      }
      __syncthreads();
      #pragma unroll 4
      for (int b = 0; b < 32; ++b) {
        float4 a = Ad[b*17+tx], e = Ae[b*17+ty];
        acc[0][0]+=a.x*e.x; acc[0][1]+=a.x*e.y; acc[0][2]+=a.x*e.z; acc[0][3]+=a.x*e.w;
        acc[1][0]+=a.y*e.x; acc[1][1]+=a.y*e.y; acc[1][2]+=a.y*e.z; acc[1][3]+=a.y*e.w;
        acc[2][0]+=a.z*e.x; acc[2][1]+=a.z*e.y; acc[2][2]+=a.z*e.z; acc[2][3]+=a.z*e.w;
        acc[3][0]+=a.w*e.x; acc[3][1]+=a.w*e.y; acc[3][2]+=a.w*e.z; acc[3][3]+=a.w*e.w;
      }
    }
    float* cz = covp + (unsigned)z*65536u;
    float4* cz4 = (float4*)cz;
    #pragma unroll
    for (int i = 0; i < 4; ++i) {
      int gd = dt*4 + tx*4 + i;
      cz4[gd*64 + et + ty] = make_float4(acc[i][0], acc[i][1], acc[i][2], acc[i][3]);
    }
    if (dt != et) {
      #pragma unroll
      for (int i = 0; i < 4; ++i) {
        int gd = dt*4 + tx*4 + i;
        #pragma unroll
        for (int j = 0; j < 4; ++j)
          cz[((et+ty)*4 + j)*256 + gd] = acc[i][j];
      }
    }
  } else if (blk == 255) {
    // rbf part 1: pd, exact median (bitonic), kxy, sumk  (LDS persists on blk)
    float* Wf   = &smemf[0];      // [32][260]
    float* pd   = &smemf[8320];
    float* sb   = &smemf[9344];
    float* sumk = &smemf[10368];
    float* hshp = &smemf[10400];
    for (int i = t; i < 8192; i += 256)
      Wf[(i>>8)*260 + (i&255)] = W[i];
    __syncthreads();
    for (int pp = t; pp < 1024; pp += 256) {
      int i = pp >> 5, j = pp & 31;
      const float4* wa = (const float4*)&Wf[i*260];
      const float4* wb = (const float4*)&Wf[j*260];
      float d2 = 0.f;
      #pragma unroll 8
      for (int c = 0; c < 64; ++c) {
        float4 a = wa[c], b = wb[c];
        float dx=a.x-b.x, dy=a.y-b.y, dz=a.z-b.z, dw=a.w-b.w;
        d2 += dx*dx + dy*dy + dz*dz + dw*dw;
      }
      pd[pp] = d2; sb[pp] = d2;
    }
    __syncthreads();
    for (int k = 2; k <= 1024; k <<= 1) {
      for (int j = k >> 1; j > 0; j >>= 1) {
        #pragma unroll 1
        for (int m = t; m < 1024; m += 256) {
          int ixj = m ^ j;
          if (ixj > m) {
            float a = sb[m], b = sb[ixj];
            bool up = ((m & k) == 0);
            if ((a > b) == up) { sb[m] = b; sb[ixj] = a; }
          }
        }
        __syncthreads();
      }
    }
    if (t == 0) hshp[0] = 0.5f*(sb[511] + sb[512]) / logf(33.0f);
    __syncthreads();
    const float h = hshp[0];
    for (int pp = t; pp < 1024; pp += 256)
      sb[pp] = expf(-pd[pp]/h);
    __syncthreads();
    if (t < 32) {
      float s = 0.f;
      #pragma unroll
      for (int j = 0; j < 32; ++j) s += sb[t*32 + j];
      sumk[t] = s;
    }
  }
  grid.sync();

  // ============ P1: H + tau | rbf part 2 (svgd) =============================
  if (blk < 128) {
    for (int rr = 0; rr < 2; ++rr) {
      const int d = blk*2 + rr;
      float sum = 0.f;
      #pragma unroll
      for (int z = 0; z < 16; ++z) sum += covp[(unsigned)z*65536u + d*256 + t];
      float h = sum * (1.f/262144.f) + ((d == t) ? 0.01f : 0.f);
      H[d*256 + t] = h;
      float a = fabsf(h);
      #pragma unroll
      for (int m = 32; m >= 1; m >>= 1) a += __shfl_xor(a, m);
      if ((t & 63) == 0) smemf[rr*4 + (t >> 6)] = a;
    }
    __syncthreads();
    if (t < 2) {
      float r = smemf[t*4] + smemf[t*4+1] + smemf[t*4+2] + smemf[t*4+3];
      atomicMax(taup, __float_as_uint(r));   // order-independent -> deterministic
    }
  } else if (blk == 255) {
    float* Wf   = &smemf[0];
    float* sb   = &smemf[9344];   // kxy
    float* sumk = &smemf[10368];
    const float h = smemf[10400];
    const float c2 = 2.f/h;
    for (int i = t; i < 8192; i += 256) {
      int n = i>>8, d = i&255;
      Wf[n*260 + d] = Wg[i] - c2*Wf[n*260 + d];
    }
    __syncthreads();
    for (int o = t; o < 8192; o += 256) {
      int oi = o>>8, oc = o&255;
      float acc = 0.f;
      #pragma unroll 8
      for (int jj = 0; jj < 32; ++jj)
        acc += sb[oi*32 + jj] * Wf[jj*260 + oc];
      float r = (acc + c2*sumk[oi]*W[o]) * (1.f/32.f);
      svgd[o] = r;
      out[2 + o] = r;     // d_out+2 only 8B aligned -> scalar stores
    }
  }
  grid.sync();

  // ============ P2: NS init =================================================
  {
    // RMW read (fetch_add 0) -> always served from the coherence point
    const float tau = __uint_as_float(
        __hip_atomic_fetch_add(taup, 0u, __ATOMIC_RELAXED, __HIP_MEMORY_SCOPE_AGENT));
    const float alpha = 2.f/(tau + 0.01f);
    const float h = H[blk*256 + t];
    Ebuf[0][blk*256 + t] = ((blk == t) ? 1.f : 0.f) - alpha*h;
    Xbuf[0][blk*256 + t] = (blk == t) ? alpha : 0.f;
  }
  grid.sync();

  // ============ P3..P8: 6 dual NS squarings (residual E^128) ================
  int cur = 0;
  for (int it = 0; it < 6; ++it) {
    if (blk < 128) {
      if (blk < 64) ns_gemm(smemf, Ebuf[cur], Ebuf[cur], nullptr, Ebuf[cur^1], blk, t);
      else          ns_gemm(smemf, Xbuf[cur], Ebuf[cur], Xbuf[cur], Xbuf[cur^1], blk-64, t);
    }
    grid.sync();
    cur ^= 1;
  }

  // ============ P9: fused final: kfac = svgd @ (X6 + X6@E6) =================
  // X6, E6 bitwise-symmetric (polynomials in H; cov mirrored, identical
  // summation order for (i,j)/(j,i)) -> column tiles read as row slices.
  if (blk < 32) {
    const float* E6 = Ebuf[cur];
    const float* X6 = Xbuf[cur];
    float* Et = smemf;            // [256][8]
    float* V  = smemf + 2048;     // [256][8]
    float* sv = smemf + 4096;     // [32][256]
    const int jc = blk*8;
    for (int i = t; i < 8192; i += 256) sv[i] = svgd[i];
    for (int i = t; i < 2048; i += 256)
      Et[i] = E6[(i>>3)*256 + jc + (i&7)];
    __syncthreads();
    float m[8];
    #pragma unroll
    for (int c = 0; c < 8; ++c) m[c] = 0.f;
    for (int r = 0; r < 256; ++r) {
      float xr = X6[r*256 + t];            // coalesced; X6[t][r] by symmetry
      #pragma unroll
      for (int c = 0; c < 8; ++c) m[c] += xr * Et[r*8 + c];
    }
    #pragma unroll
    for (int c = 0; c < 8; ++c)
      V[t*8 + c] = X6[(jc + c)*256 + t] + m[c];   // Xf[t][jc+c]
    __syncthreads();
    const int ii = t >> 3, cc = t & 7;
    float acc = 0.f;
    #pragma unroll 8
    for (int k = 0; k < 256; ++k) acc += sv[ii*256 + k] * V[k*8 + cc];
    out[2 + 8192 + ii*256 + jc + cc] = acc;
  }
}

// ---------------------------------------------------------------------------
extern "C" void kernel_launch(void* const* d_in, const int* in_sizes, int n_in,
                              void* d_out, int out_size, void* d_ws, size_t ws_size,
                              hipStream_t stream) {
  (void)in_sizes; (void)n_in; (void)out_size; (void)ws_size;
  const float4* X4 = (const float4*)d_in[0];
  const float*  y  = (const float*)d_in[1];
  const float*  W  = (const float*)d_in[2];
  float* out = (float*)d_out;
  float* ws  = (float*)d_ws;

  void* args[] = { (void*)&X4, (void*)&y, (void*)&W, (void*)&out, (void*)&ws };
  hipLaunchCooperativeKernel((const void*)k_all, dim3(NBLK), dim3(256),
                             args, 0, stream);
}

// Round 8
// 151.631 us; speedup vs baseline: 3.5630x; 2.7936x over previous
//
#include <hip/hip_runtime.h>

#define NPART 32
#define DIM   256
#define BATCH 8192

// ---- workspace offsets (float units) ----
#define OFF_S     0u          // [8192] s[b]
#define OFF_DWP   8192u       // [256][32][256] dW partials (8MB)
#define OFF_WG    2105344u    // [32][256] W_grads
#define OFF_COVP  2113536u    // [16][256][256] cov partials (full via mirror)
#define OFF_H     3162112u    // [256][256]
#define OFF_EA    3227648u    // NS E ping
#define OFF_EB    3293184u    // NS E pong
#define OFF_XA    3358720u    // NS X ping
#define OFF_XB    3424256u    // NS X pong
#define OFF_SVGD  3489792u    // [32][256]
#define OFF_LLP   3497984u    // 256 doubles (512 floats)
#define OFF_ACCP  3498496u    // 256 floats
#define OFF_TAU   3498752u    // 1 uint
#define OFF_KXY   3498760u    // [32][32] rbf kernel matrix
#define OFF_SUMK  3499784u    // [32]
#define OFF_HB    3499816u    // 1 float (bandwidth h)
// total ~14 MB of d_ws

__constant__ int c_pi[10] = {0,0,0,0,1,1,1,2,2,3};
__constant__ int c_pj[10] = {0,1,2,3,1,2,3,2,3,3};

__device__ __forceinline__ float dot4(float4 a, float4 b) {
  return a.x*b.x + a.y*b.y + a.z*b.z + a.w*b.w;
}

// ---------------------------------------------------------------------------
// D1: blocks 0-255: z = W@X^T -> dzdy -> {s, ll/acc partials, dW partials}
//     block 256:   rbf part 1: pd, exact median (bitonic), kxy, sumk -> ws
// ---------------------------------------------------------------------------
__global__ __launch_bounds__(256) void k_stage1(
    const float4* __restrict__ X4, const float* __restrict__ y,
    const float* __restrict__ W, float* __restrict__ ws)
{
  __shared__ __align__(16) float smemf[17856];   // 71.4 KB, role-overlaid
  const int t = threadIdx.x, blk = blockIdx.x;

  float* s_ws = ws + OFF_S;
  float* dWp  = ws + OFF_DWP;
  double* llp = (double*)(ws + OFF_LLP);
  float* accp = ws + OFF_ACCP;

  if (blk < 256) {
    float4* Wl  = (float4*)smemf;            // [32][65]
    float4* Xl  = (float4*)(smemf + 8320);   // [32][65]
    float*  dzl = smemf + 16640;             // [32][36]
    double* llred = (double*)(smemf + 17792);
    float*  accred = smemf + 17824;
    const int base = blk*32;
    const float4* W4 = (const float4*)W;

    if (blk == 0 && t == 0) *(unsigned*)(ws + OFF_TAU) = 0u;  // visible at kernel end

    #pragma unroll
    for (int i = 0; i < 8; ++i) { int idx = t + i*256; Wl[(idx>>6)*65 + (idx&63)] = W4[idx]; }
    #pragma unroll
    for (int i = 0; i < 8; ++i) {
      int idx = t + i*256;
      Xl[(idx>>6)*65 + (idx&63)] = X4[(base + (idx>>6))*64 + (idx&63)];
    }
    __syncthreads();

    const int nb = t & 15, bs = t >> 4;
    const int n0 = nb, n1 = nb + 16;

    float z00=0.f, z01=0.f, z10=0.f, z11=0.f;
    #pragma unroll 8
    for (int c = 0; c < 64; ++c) {
      float4 wa = Wl[n0*65+c], wb = Wl[n1*65+c];
      float4 xa = Xl[bs*65+c], xb = Xl[(bs+16)*65+c];
      z00 += dot4(wa, xa); z01 += dot4(wa, xb);
      z10 += dot4(wb, xa); z11 += dot4(wb, xb);
    }
    const int b0 = base + bs, b1 = base + bs + 16;
    const float y0 = y[b0], y1 = y[b1];

    float p00 = 1.f/(1.f+expf(-z00)), p01 = 1.f/(1.f+expf(-z01));
    float p10 = 1.f/(1.f+expf(-z10)), p11 = 1.f/(1.f+expf(-z11));

    auto dzf = [](float p, float yv) {
      float pq = p - p*p;
      return pq*(yv - p)/(pq + 1e-8f);
    };
    float dz00 = dzf(p00, y0), dz01 = dzf(p01, y1);
    float dz10 = dzf(p10, y0), dz11 = dzf(p11, y1);

    float sp0 = p00 + p10, sp1 = p01 + p11;
    float sd0 = dz00 + dz10, sd1 = dz01 + dz11;
    #pragma unroll
    for (int m = 8; m >= 1; m >>= 1) {
      sp0 += __shfl_xor(sp0, m); sp1 += __shfl_xor(sp1, m);
      sd0 += __shfl_xor(sd0, m); sd1 += __shfl_xor(sd1, m);
    }
    const float m0 = sd0*(1.f/32.f), m1 = sd1*(1.f/32.f);
    float q0 = (dz00-m0)*(dz00-m0) + (dz10-m0)*(dz10-m0);
    float q1 = (dz01-m1)*(dz01-m1) + (dz11-m1)*(dz11-m1);
    #pragma unroll
    for (int m = 8; m >= 1; m >>= 1) {
      q0 += __shfl_xor(q0, m); q1 += __shfl_xor(q1, m);
    }

    dzl[bs*36+n0]      = dz00; dzl[bs*36+n1]      = dz10;
    dzl[(bs+16)*36+n0] = dz01; dzl[(bs+16)*36+n1] = dz11;

    if (nb == 0) {
      s_ws[b0] = q0; s_ws[b1] = q1;
      float yp0 = sp0*(1.f/32.f), yp1 = sp1*(1.f/32.f);
      double ll = (double)(y0*logf(yp0+1e-3f) + (1.f-y0)*logf(1.f-yp0+1e-3f))
                + (double)(y1*logf(yp1+1e-3f) + (1.f-y1)*logf(1.f-yp1+1e-3f));
      float ac = (((y0 > 0.5f) == (yp0 > 0.5f)) ? 1.f : 0.f)
               + (((y1 > 0.5f) == (yp1 > 0.5f)) ? 1.f : 0.f);
      llred[bs] = ll; accred[bs] = ac;
    }
    __syncthreads();

    const int n = t >> 3, c = t & 7;
    float4 acc[8];
    #pragma unroll
    for (int m = 0; m < 8; ++m) acc[m] = make_float4(0.f,0.f,0.f,0.f);
    #pragma unroll 4
    for (int b = 0; b < 32; ++b) {
      float dzv = dzl[b*36+n];
      #pragma unroll
      for (int m = 0; m < 8; ++m) {
        float4 xv = Xl[b*65 + c + 8*m];
        acc[m].x += dzv*xv.x; acc[m].y += dzv*xv.y;
        acc[m].z += dzv*xv.z; acc[m].w += dzv*xv.w;
      }
    }
    float4* dWp4 = (float4*)dWp;
    #pragma unroll
    for (int m = 0; m < 8; ++m)
      dWp4[blk*2048 + n*64 + c + 8*m] = acc[m];

    if (t == 0) {
      double L = 0.0;
      for (int i = 0; i < 16; ++i) L += llred[i];
      llp[blk] = L;
    } else if (t == 1) {
      float A = 0.f;
      for (int i = 0; i < 16; ++i) A += accred[i];
      accp[blk] = A;
    }
  } else {
    // -------- rbf part 1 --------
    float* Wf   = &smemf[0];      // [32][260]
    float* pd   = &smemf[8320];   // 1024
    float* sb   = &smemf[9344];   // 1024
    for (int i = t; i < 8192; i += 256)
      Wf[(i>>8)*260 + (i&255)] = W[i];
    __syncthreads();
    for (int pp = t; pp < 1024; pp += 256) {
      int i = pp >> 5, j = pp & 31;
      const float4* wa = (const float4*)&Wf[i*260];
      const float4* wb = (const float4*)&Wf[j*260];
      float d2 = 0.f;
      #pragma unroll 8
      for (int c = 0; c < 64; ++c) {
        float4 a = wa[c], b = wb[c];
        float dx=a.x-b.x, dy=a.y-b.y, dz=a.z-b.z, dw=a.w-b.w;
        d2 += dx*dx + dy*dy + dz*dz + dw*dw;
      }
      pd[pp] = d2; sb[pp] = d2;
    }
    __syncthreads();
    for (int k = 2; k <= 1024; k <<= 1) {
      for (int j = k >> 1; j > 0; j >>= 1) {
        #pragma unroll 1
        for (int m = t; m < 1024; m += 256) {
          int ixj = m ^ j;
          if (ixj > m) {
            float a = sb[m], b = sb[ixj];
            bool up = ((m & k) == 0);
            if ((a > b) == up) { sb[m] = b; sb[ixj] = a; }
          }
        }
        __syncthreads();
      }
    }
    const float h = 0.5f*(sb[511] + sb[512]) / logf(33.0f);
    __syncthreads();
    float* kxy = ws + OFF_KXY;
    for (int pp = t; pp < 1024; pp += 256) {
      float kv = expf(-pd[pp]/h);
      sb[pp] = kv;
      kxy[pp] = kv;
    }
    __syncthreads();
    if (t < 32) {
      float s = 0.f;
      #pragma unroll
      for (int j = 0; j < 32; ++j) s += sb[t*32 + j];
      (ws + OFF_SUMK)[t] = s;
    }
    if (t == 0) (ws + OFF_HB)[0] = h;
  }
}

// ---------------------------------------------------------------------------
// D2: blocks 0-31: Wg finalize; block 32: ll/acc out; blocks 64-223: cov
// ---------------------------------------------------------------------------
__global__ __launch_bounds__(256) void k_stage2(
    const float4* __restrict__ X4, const float* __restrict__ W,
    float* __restrict__ out, float* __restrict__ ws)
{
  __shared__ __align__(16) float smemf[4480];
  const int t = threadIdx.x, blk = blockIdx.x;
  float* s_ws = ws + OFF_S;
  float* dWp  = ws + OFF_DWP;
  float* Wg   = ws + OFF_WG;
  float* covp = ws + OFF_COVP;

  if (blk < 32) {
    float sum = 0.f;
    #pragma unroll 8
    for (int k = 0; k < 256; ++k) sum += dWp[k*8192 + blk*256 + t];
    Wg[blk*256 + t] = sum - W[blk*256 + t];
  } else if (blk == 32) {
    if (t == 0) {
      const double* llp = (const double*)(ws + OFF_LLP);
      double L = 0.0;
      for (int k = 0; k < 256; ++k) L += llp[k];
      out[0] = (float)(L / 8192.0);
    } else if (t == 1) {
      const float* accp = ws + OFF_ACCP;
      float A = 0.f;
      for (int k = 0; k < 256; ++k) A += accp[k];
      out[1] = A / 8192.f;
    }
  } else if (blk >= 64) {
    float4* Ad = (float4*)&smemf[0];      // [32][17]
    float4* Ae = (float4*)&smemf[2176];   // [32][17]
    const int p = (blk - 64) >> 4, z = (blk - 64) & 15;
    const int dt = c_pi[p]*16, et = c_pj[p]*16;
    const int tx = t & 15, ty = t >> 4;
    float acc[4][4];
    #pragma unroll
    for (int i = 0; i < 4; ++i)
      #pragma unroll
      for (int j = 0; j < 4; ++j) acc[i][j] = 0.f;

    for (int sub = 0; sub < 16; ++sub) {
      const int b0 = z*512 + sub*32;
      __syncthreads();
      #pragma unroll
      for (int i = 0; i < 2; ++i) {
        int idx = t + i*256; int row = idx>>4, c4 = idx&15;
        float sv = s_ws[b0+row];
        float4 xv = X4[(b0+row)*64 + dt + c4];
        Ad[row*17+c4] = make_float4(xv.x*sv, xv.y*sv, xv.z*sv, xv.w*sv);
        Ae[row*17+c4] = X4[(b0+row)*64 + et + c4];
      }
      __syncthreads();
      #pragma unroll 4
      for (int b = 0; b < 32; ++b) {
        float4 a = Ad[b*17+tx], e = Ae[b*17+ty];
        acc[0][0]+=a.x*e.x; acc[0][1]+=a.x*e.y; acc[0][2]+=a.x*e.z; acc[0][3]+=a.x*e.w;
        acc[1][0]+=a.y*e.x; acc[1][1]+=a.y*e.y; acc[1][2]+=a.y*e.z; acc[1][3]+=a.y*e.w;
        acc[2][0]+=a.z*e.x; acc[2][1]+=a.z*e.y; acc[2][2]+=a.z*e.z; acc[2][3]+=a.z*e.w;
        acc[3][0]+=a.w*e.x; acc[3][1]+=a.w*e.y; acc[3][2]+=a.w*e.z; acc[3][3]+=a.w*e.w;
      }
    }
    float* cz = covp + (unsigned)z*65536u;
    float4* cz4 = (float4*)cz;
    #pragma unroll
    for (int i = 0; i < 4; ++i) {
      int gd = dt*4 + tx*4 + i;
      cz4[gd*64 + et + ty] = make_float4(acc[i][0], acc[i][1], acc[i][2], acc[i][3]);
    }
    if (dt != et) {   // mirror write -> cov bitwise symmetric
      #pragma unroll
      for (int i = 0; i < 4; ++i) {
        int gd = dt*4 + tx*4 + i;
        #pragma unroll
        for (int j = 0; j < 4; ++j)
          cz[((et+ty)*4 + j)*256 + gd] = acc[i][j];
      }
    }
  }
}

// ---------------------------------------------------------------------------
// D3: blocks 0-127: H (2 rows each) + Gershgorin tau; blocks 128-159: svgd
// ---------------------------------------------------------------------------
__global__ __launch_bounds__(256) void k_stage3(
    const float* __restrict__ W, float* __restrict__ out,
    float* __restrict__ ws)
{
  __shared__ __align__(16) float smemf[8300];
  const int t = threadIdx.x, blk = blockIdx.x;
  float* covp = ws + OFF_COVP;
  float* H    = ws + OFF_H;

  if (blk < 128) {
    for (int rr = 0; rr < 2; ++rr) {
      const int d = blk*2 + rr;
      float sum = 0.f;
      #pragma unroll
      for (int z = 0; z < 16; ++z) sum += covp[(unsigned)z*65536u + d*256 + t];
      float h = sum * (1.f/262144.f) + ((d == t) ? 0.01f : 0.f);
      H[d*256 + t] = h;
      float a = fabsf(h);
      #pragma unroll
      for (int m = 32; m >= 1; m >>= 1) a += __shfl_xor(a, m);
      if ((t & 63) == 0) smemf[rr*4 + (t >> 6)] = a;
    }
    __syncthreads();
    if (t < 2) {
      float r = smemf[t*4] + smemf[t*4+1] + smemf[t*4+2] + smemf[t*4+3];
      atomicMax((unsigned*)(ws + OFF_TAU), __float_as_uint(r));  // commutative
    }
  } else {
    // svgd row i = blk-128: (kxy@(Wg - c2 W) + c2 sumk.*W)/32
    const int i = blk - 128;
    float* G   = &smemf[0];       // [32][257]
    float* kxr = &smemf[8224];    // 32
    const float* Wg  = ws + OFF_WG;
    const float h = (ws + OFF_HB)[0];
    const float c2 = 2.f/h;
    for (int idx = t; idx < 8192; idx += 256) {
      int j = idx >> 8, d = idx & 255;
      G[j*257 + d] = Wg[idx] - c2*W[idx];
    }
    if (t < 32) kxr[t] = (ws + OFF_KXY)[i*32 + t];
    __syncthreads();
    float acc = 0.f;
    #pragma unroll 8
    for (int j = 0; j < 32; ++j) acc += kxr[j] * G[j*257 + t];
    float r = (acc + c2*(ws + OFF_SUMK)[i]*W[i*256 + t]) * (1.f/32.f);
    (ws + OFF_SVGD)[i*256 + t] = r;
    out[2 + i*256 + t] = r;   // d_out+2 only 8B aligned -> scalar store
  }
}

// ---------------------------------------------------------------------------
// NS init (R5-proven): E0 = I - alpha*H ; X0 = alpha*I. grid 256.
// Consistency E0 = I - H@X0 holds BY CONSTRUCTION -> NS limit is exactly Hinv.
// ---------------------------------------------------------------------------
__global__ __launch_bounds__(256) void k_nsinit(float* __restrict__ ws)
{
  const int d = blockIdx.x, t = threadIdx.x;
  const float tau = __uint_as_float(*(const unsigned*)(ws + OFF_TAU));
  const float alpha = 2.f/(tau + 0.01f);
  const float h = (ws + OFF_H)[d*256 + t];
  (ws + OFF_EA)[d*256 + t] = ((d == t) ? 1.f : 0.f) - alpha*h;
  (ws + OFF_XA)[d*256 + t] = (d == t) ? alpha : 0.f;
}

// ---------------------------------------------------------------------------
// NS GEMM tile helper: 32x32 tile of Cout = (Cadd? Cadd + A@B : A@B), 256x256
// ---------------------------------------------------------------------------
__device__ __forceinline__ void ns_gemm(
    float* smemf, const float* __restrict__ A, const float* __restrict__ B,
    const float* __restrict__ Cadd, float* __restrict__ Cout,
    int tileid, int t)
{
  float* At = smemf;          // [32][34] transposed A tile
  float* Bs = smemf + 1088;   // [32][34]
  const int i0 = (tileid >> 3)*32, j0 = (tileid & 7)*32;
  const int ti = t & 15, tj = t >> 4;
  const int srow = t >> 3, sc4 = t & 7;
  const float4* A4 = (const float4*)A;
  const float4* B4 = (const float4*)B;
  float acc00=0.f, acc01=0.f, acc10=0.f, acc11=0.f;

  for (int k0 = 0; k0 < 8; ++k0) {
    __syncthreads();
    float4 av = A4[(i0+srow)*64 + k0*8 + sc4];
    float4 bv = B4[(k0*32+srow)*64 + (j0>>2) + sc4];
    At[(sc4*4+0)*34+srow]=av.x; At[(sc4*4+1)*34+srow]=av.y;
    At[(sc4*4+2)*34+srow]=av.z; At[(sc4*4+3)*34+srow]=av.w;
    Bs[srow*34+sc4*4+0]=bv.x; Bs[srow*34+sc4*4+1]=bv.y;
    Bs[srow*34+sc4*4+2]=bv.z; Bs[srow*34+sc4*4+3]=bv.w;
    __syncthreads();
    #pragma unroll
    for (int kk = 0; kk < 32; ++kk) {
      float2 a = *(const float2*)&At[kk*34+2*ti];
      float2 b = *(const float2*)&Bs[kk*34+2*tj];
      acc00 += a.x*b.x; acc01 += a.x*b.y;
      acc10 += a.y*b.x; acc11 += a.y*b.y;
    }
  }
  const int gi = i0 + 2*ti, gj = j0 + 2*tj;
  if (Cadd) {
    Cout[gi*256+gj]       = Cadd[gi*256+gj]       + acc00;
    Cout[gi*256+gj+1]     = Cadd[gi*256+gj+1]     + acc01;
    Cout[(gi+1)*256+gj]   = Cadd[(gi+1)*256+gj]   + acc10;
    Cout[(gi+1)*256+gj+1] = Cadd[(gi+1)*256+gj+1] + acc11;
  } else {
    Cout[gi*256+gj]       = acc00; Cout[gi*256+gj+1]     = acc01;
    Cout[(gi+1)*256+gj]   = acc10; Cout[(gi+1)*256+gj+1] = acc11;
  }
}

// ---------------------------------------------------------------------------
// NS dual: blocks 0-63: Enew = E@E ; blocks 64-127: Xnew = X + X@E
// ---------------------------------------------------------------------------
__global__ __launch_bounds__(256) void k_nsdual(
    const float* __restrict__ E, const float* __restrict__ Xm,
    float* __restrict__ Enew, float* __restrict__ Xnew)
{
  __shared__ __align__(16) float smemf[2176];
  const int t = threadIdx.x, blk = blockIdx.x;
  if (blk < 64) ns_gemm(smemf, E, E, nullptr, Enew, blk, t);
  else          ns_gemm(smemf, Xm, E, Xm, Xnew, blk - 64, t);
}

// ---------------------------------------------------------------------------
// J: kfac = svgd @ (X + X@E)  (X,E bitwise symmetric -> column reads as rows)
// grid 32
// ---------------------------------------------------------------------------
__global__ __launch_bounds__(256) void k_kfac(
    const float* __restrict__ E, const float* __restrict__ X,
    float* __restrict__ out, float* __restrict__ ws)
{
  __shared__ __align__(16) float smemf[12288];
  const int t = threadIdx.x, blk = blockIdx.x;
  const float* svgd = ws + OFF_SVGD;
  float* Et = smemf;            // [256][8]
  float* V  = smemf + 2048;     // [256][8]
  float* sv = smemf + 4096;     // [32][256]
  const int jc = blk*8;
  for (int i = t; i < 8192; i += 256) sv[i] = svgd[i];
  for (int i = t; i < 2048; i += 256)
    Et[i] = E[(i>>3)*256 + jc + (i&7)];
  __syncthreads();
  float m[8];
  #pragma unroll
  for (int c = 0; c < 8; ++c) m[c] = 0.f;
  for (int r = 0; r < 256; ++r) {
    float xr = X[r*256 + t];             // coalesced; X[t][r] by symmetry
    #pragma unroll
    for (int c = 0; c < 8; ++c) m[c] += xr * Et[r*8 + c];
  }
  #pragma unroll
  for (int c = 0; c < 8; ++c)
    V[t*8 + c] = X[(jc + c)*256 + t] + m[c];   // Xfinal[t][jc+c]
  __syncthreads();
  const int ii = t >> 3, cc = t & 7;
  float acc = 0.f;
  #pragma unroll 8
  for (int k = 0; k < 256; ++k) acc += sv[ii*256 + k] * V[k*8 + cc];
  out[2 + 8192 + ii*256 + jc + cc] = acc;
}

// ---------------------------------------------------------------------------
extern "C" void kernel_launch(void* const* d_in, const int* in_sizes, int n_in,
                              void* d_out, int out_size, void* d_ws, size_t ws_size,
                              hipStream_t stream) {
  (void)in_sizes; (void)n_in; (void)out_size; (void)ws_size;
  const float* X = (const float*)d_in[0];
  const float* y = (const float*)d_in[1];
  const float* W = (const float*)d_in[2];
  float* out = (float*)d_out;
  float* ws  = (float*)d_ws;

  float* EA = ws + OFF_EA; float* EB = ws + OFF_EB;
  float* XA = ws + OFF_XA; float* XB = ws + OFF_XB;

  k_stage1<<<257, 256, 0, stream>>>((const float4*)X, y, W, ws);
  k_stage2<<<224, 256, 0, stream>>>((const float4*)X, W, out, ws);
  k_stage3<<<160, 256, 0, stream>>>(W, out, ws);
  k_nsinit<<<256, 256, 0, stream>>>(ws);                    // (E0, X0) in EA/XA
  k_nsdual<<<128, 256, 0, stream>>>(EA, XA, EB, XB);        // (E1, X1)
  k_nsdual<<<128, 256, 0, stream>>>(EB, XB, EA, XA);        // (E2, X2)
  k_nsdual<<<128, 256, 0, stream>>>(EA, XA, EB, XB);        // (E3, X3)
  k_nsdual<<<128, 256, 0, stream>>>(EB, XB, EA, XA);        // (E4, X4)
  k_nsdual<<<128, 256, 0, stream>>>(EA, XA, EB, XB);        // (E5, X5)
  k_nsdual<<<128, 256, 0, stream>>>(EB, XB, EA, XA);        // (E6, X6)
  k_kfac<<<32, 256, 0, stream>>>(EA, XA, out, ws);          // X7: resid E0^128
}

// Round 9
// 139.491 us; speedup vs baseline: 3.8731x; 1.0870x over previous
//
#include <hip/hip_runtime.h>

#define NPART 32
#define DIM   256
#define BATCH 8192

// ---- workspace offsets (float units) ----
#define OFF_S     0u          // [8192] s[b]
#define OFF_DWP   8192u       // [512][32][256] dW partials (16MB)
#define OFF_WG    4202496u    // [32][256] W_grads
#define OFF_COVP  4210688u    // [64][256][256] cov partials (16MB, full via mirror)
#define OFF_H     8404992u    // [256][256]
#define OFF_EA    8470528u    // NS E ping
#define OFF_EB    8536064u    // NS E pong
#define OFF_XA    8601600u    // NS X ping
#define OFF_XB    8667136u    // NS X pong
#define OFF_SVGD  8732672u    // [32][256]
#define OFF_LLP   8740864u    // 512 doubles (1024 floats)
#define OFF_ACCP  8741888u    // 512 floats
#define OFF_TAU   8742400u    // 1 uint
#define OFF_KXY   8742404u    // [32][32] rbf kernel matrix
#define OFF_SUMK  8743428u    // [32]
#define OFF_HB    8743460u    // 1 float (bandwidth h)
// total ~35 MB of d_ws

__constant__ int c_pi[10] = {0,0,0,0,1,1,1,2,2,3};
__constant__ int c_pj[10] = {0,1,2,3,1,2,3,2,3,3};

__device__ __forceinline__ float dot4(float4 a, float4 b) {
  return a.x*b.x + a.y*b.y + a.z*b.z + a.w*b.w;
}

// ---------------------------------------------------------------------------
// D1 (grid 513 x 512 threads):
//   block 0:      rbf part 1: pd, exact median (bitonic), kxy, sumk -> ws
//   blocks 1-512: chunk = blk-1 (16 batch rows): z = W@X^T -> dzdy ->
//                 {s, ll/acc partials, dW partials}
// 512-thr/52.5KB-LDS: 2-3 blocks/CU co-resident -> 16-24 waves/CU (R8: 4).
// ---------------------------------------------------------------------------
__global__ __launch_bounds__(512) void k_stage1(
    const float4* __restrict__ X4, const float* __restrict__ y,
    const float* __restrict__ W, float* __restrict__ ws)
{
  __shared__ __align__(16) float smemf[13120];   // 52.5 KB, role-overlaid
  const int t = threadIdx.x, blk = blockIdx.x;

  float* s_ws = ws + OFF_S;
  float* dWp  = ws + OFF_DWP;
  double* llp = (double*)(ws + OFF_LLP);
  float* accp = ws + OFF_ACCP;

  if (blk > 0) {
    float4* Wl  = (float4*)smemf;             // [32][65]
    float4* Xl  = (float4*)(smemf + 8320);    // [16][65]
    float*  dzl = smemf + 12480;              // [16][36]
    double* llred = (double*)(smemf + 13056); // 16 doubles
    float*  accred = smemf + 13088;           // 16
    const int chunk = blk - 1;
    const int base = chunk*16;
    const float4* W4 = (const float4*)W;

    #pragma unroll
    for (int i = 0; i < 4; ++i) {
      int idx = t + i*512;
      Wl[(idx>>6)*65 + (idx&63)] = W4[idx];
    }
    #pragma unroll
    for (int i = 0; i < 2; ++i) {
      int idx = t + i*512;
      Xl[(idx>>6)*65 + (idx&63)] = X4[(base + (idx>>6))*64 + (idx&63)];
    }
    __syncthreads();

    const int n = t & 31, b = t >> 5;    // wave = 2 batch rows x 32 particles
    float z = 0.f;
    #pragma unroll 8
    for (int c = 0; c < 64; ++c)
      z += dot4(Wl[n*65 + c], Xl[b*65 + c]);

    const int gb = base + b;
    const float yv = y[gb];
    const float p = 1.f/(1.f + expf(-z));
    const float pq = p - p*p;
    const float dz = pq*(yv - p)/(pq + 1e-8f);

    // particle-axis reductions: masks <32 stay within each 32-lane b-group
    float sp = p, sd = dz;
    #pragma unroll
    for (int m = 16; m >= 1; m >>= 1) {
      sp += __shfl_xor(sp, m); sd += __shfl_xor(sd, m);
    }
    const float mean = sd*(1.f/32.f);
    float q = (dz - mean)*(dz - mean);
    #pragma unroll
    for (int m = 16; m >= 1; m >>= 1) q += __shfl_xor(q, m);

    dzl[b*36 + n] = dz;

    if (n == 0) {
      s_ws[gb] = q;
      float yp = sp*(1.f/32.f);
      llred[b] = (double)(yv*logf(yp+1e-3f) + (1.f-yv)*logf(1.f-yp+1e-3f));
      accred[b] = ((yv > 0.5f) == (yp > 0.5f)) ? 1.f : 0.f;
    }
    __syncthreads();

    // dW partials: dWp[chunk][n2][d] = sum_b dzl[b][n2] * Xl[b][d]
    const int n2 = t >> 4, c = t & 15;
    float4 acc[4];
    #pragma unroll
    for (int m = 0; m < 4; ++m) acc[m] = make_float4(0.f,0.f,0.f,0.f);
    #pragma unroll
    for (int b2 = 0; b2 < 16; ++b2) {
      float dzv = dzl[b2*36 + n2];
      #pragma unroll
      for (int m = 0; m < 4; ++m) {
        float4 xv = Xl[b2*65 + c + 16*m];
        acc[m].x += dzv*xv.x; acc[m].y += dzv*xv.y;
        acc[m].z += dzv*xv.z; acc[m].w += dzv*xv.w;
      }
    }
    float4* dWp4 = (float4*)dWp;
    #pragma unroll
    for (int m = 0; m < 4; ++m)
      dWp4[chunk*2048 + n2*64 + c + 16*m] = acc[m];

    if (t == 0) {
      double L = 0.0;
      for (int i = 0; i < 16; ++i) L += llred[i];
      llp[chunk] = L;
    } else if (t == 1) {
      float A = 0.f;
      for (int i = 0; i < 16; ++i) A += accred[i];
      accp[chunk] = A;
    }
  } else {
    // -------- block 0: rbf part 1 --------
    if (t == 0) *(unsigned*)(ws + OFF_TAU) = 0u;   // visible at kernel end
    float* Wf = &smemf[0];      // [32][260]
    float* pd = &smemf[8320];   // 1024
    float* sb = &smemf[9344];   // 1024
    for (int i = t; i < 8192; i += 512)
      Wf[(i>>8)*260 + (i&255)] = W[i];
    __syncthreads();
    for (int pp = t; pp < 1024; pp += 512) {
      int i = pp >> 5, j = pp & 31;
      const float4* wa = (const float4*)&Wf[i*260];
      const float4* wb = (const float4*)&Wf[j*260];
      float d2 = 0.f;
      #pragma unroll 8
      for (int c = 0; c < 64; ++c) {
        float4 a = wa[c], b = wb[c];
        float dx=a.x-b.x, dy=a.y-b.y, dz=a.z-b.z, dw=a.w-b.w;
        d2 += dx*dx + dy*dy + dz*dz + dw*dw;
      }
      pd[pp] = d2; sb[pp] = d2;
    }
    __syncthreads();
    for (int k = 2; k <= 1024; k <<= 1) {
      for (int j = k >> 1; j > 0; j >>= 1) {
        #pragma unroll 1
        for (int m = t; m < 1024; m += 512) {
          int ixj = m ^ j;
          if (ixj > m) {
            float a = sb[m], b = sb[ixj];
            bool up = ((m & k) == 0);
            if ((a > b) == up) { sb[m] = b; sb[ixj] = a; }
          }
        }
        __syncthreads();
      }
    }
    const float h = 0.5f*(sb[511] + sb[512]) / logf(33.0f);
    __syncthreads();
    float* kxy = ws + OFF_KXY;
    for (int pp = t; pp < 1024; pp += 512) {
      float kv = expf(-pd[pp]/h);
      sb[pp] = kv;
      kxy[pp] = kv;
    }
    __syncthreads();
    if (t < 32) {
      float s = 0.f;
      #pragma unroll
      for (int j = 0; j < 32; ++j) s += sb[t*32 + j];
      (ws + OFF_SUMK)[t] = s;
    }
    if (t == 0) (ws + OFF_HB)[0] = h;
  }
}

// ---------------------------------------------------------------------------
// D2 (grid 704 x 256): blocks 0-31 Wg finalize; 32 ll/acc; 64-703 cov
// cov: 10 tile-pairs x 64 K-chunks of 128 rows (4 subs) -> ~2.5 blocks/CU
// ---------------------------------------------------------------------------
__global__ __launch_bounds__(256) void k_stage2(
    const float4* __restrict__ X4, const float* __restrict__ W,
    float* __restrict__ out, float* __restrict__ ws)
{
  __shared__ __align__(16) float smemf[4480];
  const int t = threadIdx.x, blk = blockIdx.x;
  float* s_ws = ws + OFF_S;
  float* dWp  = ws + OFF_DWP;
  float* Wg   = ws + OFF_WG;
  float* covp = ws + OFF_COVP;

  if (blk < 32) {
    float sum = 0.f;
    #pragma unroll 8
    for (int k = 0; k < 512; ++k) sum += dWp[k*8192 + blk*256 + t];
    Wg[blk*256 + t] = sum - W[blk*256 + t];
  } else if (blk == 32) {
    if (t == 0) {
      const double* llp = (const double*)(ws + OFF_LLP);
      double L = 0.0;
      for (int k = 0; k < 512; ++k) L += llp[k];
      out[0] = (float)(L / 8192.0);
    } else if (t == 1) {
      const float* accp = ws + OFF_ACCP;
      float A = 0.f;
      for (int k = 0; k < 512; ++k) A += accp[k];
      out[1] = A / 8192.f;
    }
  } else if (blk >= 64) {
    float4* Ad = (float4*)&smemf[0];      // [32][17]
    float4* Ae = (float4*)&smemf[2176];   // [32][17]
    const int p = (blk - 64) >> 6, z = (blk - 64) & 63;
    const int dt = c_pi[p]*16, et = c_pj[p]*16;
    const int tx = t & 15, ty = t >> 4;
    float acc[4][4];
    #pragma unroll
    for (int i = 0; i < 4; ++i)
      #pragma unroll
      for (int j = 0; j < 4; ++j) acc[i][j] = 0.f;

    for (int sub = 0; sub < 4; ++sub) {
      const int b0 = z*128 + sub*32;
      __syncthreads();
      #pragma unroll
      for (int i = 0; i < 2; ++i) {
        int idx = t + i*256; int row = idx>>4, c4 = idx&15;
        float sv = s_ws[b0+row];
        float4 xv = X4[(b0+row)*64 + dt + c4];
        Ad[row*17+c4] = make_float4(xv.x*sv, xv.y*sv, xv.z*sv, xv.w*sv);
        Ae[row*17+c4] = X4[(b0+row)*64 + et + c4];
      }
      __syncthreads();
      #pragma unroll 4
      for (int b = 0; b < 32; ++b) {
        float4 a = Ad[b*17+tx], e = Ae[b*17+ty];
        acc[0][0]+=a.x*e.x; acc[0][1]+=a.x*e.y; acc[0][2]+=a.x*e.z; acc[0][3]+=a.x*e.w;
        acc[1][0]+=a.y*e.x; acc[1][1]+=a.y*e.y; acc[1][2]+=a.y*e.z; acc[1][3]+=a.y*e.w;
        acc[2][0]+=a.z*e.x; acc[2][1]+=a.z*e.y; acc[2][2]+=a.z*e.z; acc[2][3]+=a.z*e.w;
        acc[3][0]+=a.w*e.x; acc[3][1]+=a.w*e.y; acc[3][2]+=a.w*e.z; acc[3][3]+=a.w*e.w;
      }
    }
    float* cz = covp + (unsigned)z*65536u;
    float4* cz4 = (float4*)cz;
    #pragma unroll
    for (int i = 0; i < 4; ++i) {
      int gd = dt*4 + tx*4 + i;
      cz4[gd*64 + et + ty] = make_float4(acc[i][0], acc[i][1], acc[i][2], acc[i][3]);
    }
    if (dt != et) {   // mirror write -> covp slab bitwise symmetric
      #pragma unroll
      for (int i = 0; i < 4; ++i) {
        int gd = dt*4 + tx*4 + i;
        #pragma unroll
        for (int j = 0; j < 4; ++j)
          cz[((et+ty)*4 + j)*256 + gd] = acc[i][j];
      }
    }
  }
}

// ---------------------------------------------------------------------------
// D3 (grid 288 x 256): blocks 0-255: H row + Gershgorin tau; 256-287: svgd
// ---------------------------------------------------------------------------
__global__ __launch_bounds__(256) void k_stage3(
    const float* __restrict__ W, float* __restrict__ out,
    float* __restrict__ ws)
{
  __shared__ __align__(16) float smemf[8300];
  const int t = threadIdx.x, blk = blockIdx.x;
  float* covp = ws + OFF_COVP;
  float* H    = ws + OFF_H;

  if (blk < 256) {
    const int d = blk;
    float sum = 0.f;
    #pragma unroll 8
    for (int z = 0; z < 64; ++z) sum += covp[(unsigned)z*65536u + d*256 + t];
    float h = sum * (1.f/262144.f) + ((d == t) ? 0.01f : 0.f);
    H[d*256 + t] = h;
    float a = fabsf(h);
    #pragma unroll
    for (int m = 32; m >= 1; m >>= 1) a += __shfl_xor(a, m);
    if ((t & 63) == 0) smemf[t >> 6] = a;
    __syncthreads();
    if (t == 0) {
      float r = smemf[0] + smemf[1] + smemf[2] + smemf[3];
      atomicMax((unsigned*)(ws + OFF_TAU), __float_as_uint(r));  // commutative
    }
  } else {
    // svgd row i: (kxy@(Wg - c2 W) + c2 sumk.*W)/32
    const int i = blk - 256;
    float* G   = &smemf[0];       // [32][257]
    float* kxr = &smemf[8224];    // 32
    const float* Wg  = ws + OFF_WG;
    const float h = (ws + OFF_HB)[0];
    const float c2 = 2.f/h;
    for (int idx = t; idx < 8192; idx += 256) {
      int j = idx >> 8, d = idx & 255;
      G[j*257 + d] = Wg[idx] - c2*W[idx];
    }
    if (t < 32) kxr[t] = (ws + OFF_KXY)[i*32 + t];
    __syncthreads();
    float acc = 0.f;
    #pragma unroll 8
    for (int j = 0; j < 32; ++j) acc += kxr[j] * G[j*257 + t];
    float r = (acc + c2*(ws + OFF_SUMK)[i]*W[i*256 + t]) * (1.f/32.f);
    (ws + OFF_SVGD)[i*256 + t] = r;
    out[2 + i*256 + t] = r;   // d_out+2 only 8B aligned -> scalar store
  }
}

// ---------------------------------------------------------------------------
// NS init (proven): E0 = I - alpha*H ; X0 = alpha*I. grid 256.
// Consistency E0 = I - H@X0 holds BY CONSTRUCTION -> NS limit is exactly Hinv.
// ---------------------------------------------------------------------------
__global__ __launch_bounds__(256) void k_nsinit(float* __restrict__ ws)
{
  const int d = blockIdx.x, t = threadIdx.x;
  const float tau = __uint_as_float(*(const unsigned*)(ws + OFF_TAU));
  const float alpha = 2.f/(tau + 0.01f);
  const float h = (ws + OFF_H)[d*256 + t];
  (ws + OFF_EA)[d*256 + t] = ((d == t) ? 1.f : 0.f) - alpha*h;
  (ws + OFF_XA)[d*256 + t] = (d == t) ? alpha : 0.f;
}

// ---------------------------------------------------------------------------
// NS GEMM tile helper: 32x32 tile of Cout = (Cadd? Cadd + A@B : A@B), 256x256
// ---------------------------------------------------------------------------
__device__ __forceinline__ void ns_gemm(
    float* smemf, const float* __restrict__ A, const float* __restrict__ B,
    const float* __restrict__ Cadd, float* __restrict__ Cout,
    int tileid, int t)
{
  float* At = smemf;          // [32][34] transposed A tile
  float* Bs = smemf + 1088;   // [32][34]
  const int i0 = (tileid >> 3)*32, j0 = (tileid & 7)*32;
  const int ti = t & 15, tj = t >> 4;
  const int srow = t >> 3, sc4 = t & 7;
  const float4* A4 = (const float4*)A;
  const float4* B4 = (const float4*)B;
  float acc00=0.f, acc01=0.f, acc10=0.f, acc11=0.f;

  for (int k0 = 0; k0 < 8; ++k0) {
    __syncthreads();
    float4 av = A4[(i0+srow)*64 + k0*8 + sc4];
    float4 bv = B4[(k0*32+srow)*64 + (j0>>2) + sc4];
    At[(sc4*4+0)*34+srow]=av.x; At[(sc4*4+1)*34+srow]=av.y;
    At[(sc4*4+2)*34+srow]=av.z; At[(sc4*4+3)*34+srow]=av.w;
    Bs[srow*34+sc4*4+0]=bv.x; Bs[srow*34+sc4*4+1]=bv.y;
    Bs[srow*34+sc4*4+2]=bv.z; Bs[srow*34+sc4*4+3]=bv.w;
    __syncthreads();
    #pragma unroll
    for (int kk = 0; kk < 32; ++kk) {
      float2 a = *(const float2*)&At[kk*34+2*ti];
      float2 b = *(const float2*)&Bs[kk*34+2*tj];
      acc00 += a.x*b.x; acc01 += a.x*b.y;
      acc10 += a.y*b.x; acc11 += a.y*b.y;
    }
  }
  const int gi = i0 + 2*ti, gj = j0 + 2*tj;
  if (Cadd) {
    Cout[gi*256+gj]       = Cadd[gi*256+gj]       + acc00;
    Cout[gi*256+gj+1]     = Cadd[gi*256+gj+1]     + acc01;
    Cout[(gi+1)*256+gj]   = Cadd[(gi+1)*256+gj]   + acc10;
    Cout[(gi+1)*256+gj+1] = Cadd[(gi+1)*256+gj+1] + acc11;
  } else {
    Cout[gi*256+gj]       = acc00; Cout[gi*256+gj+1]     = acc01;
    Cout[(gi+1)*256+gj]   = acc10; Cout[(gi+1)*256+gj+1] = acc11;
  }
}

// ---------------------------------------------------------------------------
// NS dual: blocks 0-63: Enew = E@E ; blocks 64-127: Xnew = X + X@E
// ---------------------------------------------------------------------------
__global__ __launch_bounds__(256) void k_nsdual(
    const float* __restrict__ E, const float* __restrict__ Xm,
    float* __restrict__ Enew, float* __restrict__ Xnew)
{
  __shared__ __align__(16) float smemf[2176];
  const int t = threadIdx.x, blk = blockIdx.x;
  if (blk < 64) ns_gemm(smemf, E, E, nullptr, Enew, blk, t);
  else          ns_gemm(smemf, Xm, E, Xm, Xnew, blk - 64, t);
}

// ---------------------------------------------------------------------------
// J: kfac = svgd @ (X + X@E)  (X,E bitwise symmetric -> column reads as rows)
// grid 32
// ---------------------------------------------------------------------------
__global__ __launch_bounds__(256) void k_kfac(
    const float* __restrict__ E, const float* __restrict__ X,
    float* __restrict__ out, float* __restrict__ ws)
{
  __shared__ __align__(16) float smemf[12288];
  const int t = threadIdx.x, blk = blockIdx.x;
  const float* svgd = ws + OFF_SVGD;
  float* Et = smemf;            // [256][8]
  float* V  = smemf + 2048;     // [256][8]
  float* sv = smemf + 4096;     // [32][256]
  const int jc = blk*8;
  for (int i = t; i < 8192; i += 256) sv[i] = svgd[i];
  for (int i = t; i < 2048; i += 256)
    Et[i] = E[(i>>3)*256 + jc + (i&7)];
  __syncthreads();
  float m[8];
  #pragma unroll
  for (int c = 0; c < 8; ++c) m[c] = 0.f;
  for (int r = 0; r < 256; ++r) {
    float xr = X[r*256 + t];             // coalesced; X[t][r] by symmetry
    #pragma unroll
    for (int c = 0; c < 8; ++c) m[c] += xr * Et[r*8 + c];
  }
  #pragma unroll
  for (int c = 0; c < 8; ++c)
    V[t*8 + c] = X[(jc + c)*256 + t] + m[c];   // Xfinal[t][jc+c]
  __syncthreads();
  const int ii = t >> 3, cc = t & 7;
  float acc = 0.f;
  #pragma unroll 8
  for (int k = 0; k < 256; ++k) acc += sv[ii*256 + k] * V[k*8 + cc];
  out[2 + 8192 + ii*256 + jc + cc] = acc;
}

// ---------------------------------------------------------------------------
extern "C" void kernel_launch(void* const* d_in, const int* in_sizes, int n_in,
                              void* d_out, int out_size, void* d_ws, size_t ws_size,
                              hipStream_t stream) {
  (void)in_sizes; (void)n_in; (void)out_size; (void)ws_size;
  const float* X = (const float*)d_in[0];
  const float* y = (const float*)d_in[1];
  const float* W = (const float*)d_in[2];
  float* out = (float*)d_out;
  float* ws  = (float*)d_ws;

  float* EA = ws + OFF_EA; float* EB = ws + OFF_EB;
  float* XA = ws + OFF_XA; float* XB = ws + OFF_XB;

  k_stage1<<<513, 512, 0, stream>>>((const float4*)X, y, W, ws);
  k_stage2<<<704, 256, 0, stream>>>((const float4*)X, W, out, ws);
  k_stage3<<<288, 256, 0, stream>>>(W, out, ws);
  k_nsinit<<<256, 256, 0, stream>>>(ws);                    // (E0, X0) in EA/XA
  k_nsdual<<<128, 256, 0, stream>>>(EA, XA, EB, XB);        // (E1, X1)
  k_nsdual<<<128, 256, 0, stream>>>(EB, XB, EA, XA);        // (E2, X2)
  k_nsdual<<<128, 256, 0, stream>>>(EA, XA, EB, XB);        // (E3, X3)
  k_nsdual<<<128, 256, 0, stream>>>(EB, XB, EA, XA);        // (E4, X4)
  k_nsdual<<<128, 256, 0, stream>>>(EA, XA, EB, XB);        // (E5, X5)
  k_nsdual<<<128, 256, 0, stream>>>(EB, XB, EA, XA);        // (E6, X6)
  k_kfac<<<32, 256, 0, stream>>>(EA, XA, out, ws);          // X7: resid E0^128
}